// Round 6
// baseline (250.189 us; speedup 1.0000x reference)
//
#include <hip/hip_runtime.h>
#include <stdint.h>

#define SQ  2048
#define DD  128
#define KVB 64
#define WAVES 4
#define QB  128          // q rows per block (32 per wave)

#define KS 136           // K tile row stride (elems): 272B rows, 16B-aligned
#define VS 72            // V^T row stride: 144B rows, 16B-aligned
#define PS 72            // P row stride

typedef __attribute__((ext_vector_type(8))) __bf16 bf16x8;
typedef __attribute__((ext_vector_type(4))) float  f32x4;

#define MFMA(a,b,c) __builtin_amdgcn_mfma_f32_16x16x32_bf16((a),(b),(c),0,0,0)

__device__ __forceinline__ bf16x8 cvt8(float4 f0, float4 f1) {
    bf16x8 v;
    v[0]=(__bf16)f0.x; v[1]=(__bf16)f0.y; v[2]=(__bf16)f0.z; v[3]=(__bf16)f0.w;
    v[4]=(__bf16)f1.x; v[5]=(__bf16)f1.y; v[6]=(__bf16)f1.z; v[7]=(__bf16)f1.w;
    return v;
}

__global__ __launch_bounds__(256, 2)
void attn_fwd(const float* __restrict__ x1, const float* __restrict__ x2,
              float* __restrict__ out)
{
    constexpr float CEXP = 0.08838834764831843f * 1.4426950408889634f; // scale*log2(e)

    __shared__ __bf16 kt[KVB][KS];        // K[k][d] row-major          (17.4 KB)
    __shared__ __bf16 vt[DD][VS];         // V^T[d][k ^ 8*((d>>3)&7)]   (18.4 KB)
    __shared__ __bf16 pt[WAVES][32][PS];  // P[q][k] per wave           (18.4 KB)

    const int tid = threadIdx.x;
    const int w   = tid >> 6;
    const int l   = tid & 63;
    const int lr  = l & 15;
    const int g   = l >> 4;

    const int bh  = blockIdx.y;
    const int q0w = blockIdx.x * QB + w * 32;

    const float* Qp = x1 + (size_t)bh * SQ * DD;
    const float* Kp = x2 + (size_t)bh * SQ * DD;
    float*       Op = out + (size_t)bh * SQ * DD;

    // ---- Q fragments in registers: A row = lr, kappa chunk = g*8 ----
    bf16x8 aq[2][4];
    #pragma unroll
    for (int m = 0; m < 2; ++m) {
        const float* qrow = Qp + (size_t)(q0w + 16*m + lr) * DD;
        #pragma unroll
        for (int c = 0; c < 4; ++c) {
            const float4* p4 = (const float4*)(qrow + 32*c + g*8);
            aq[m][c] = cvt8(p4[0], p4[1]);
        }
    }

    f32x4 o[2][8];
    #pragma unroll
    for (int m=0;m<2;++m) for (int n=0;n<8;++n) o[m][n] = (f32x4)(0.0f);
    float mrun[2][4], lrun[2][4];
    #pragma unroll
    for (int m=0;m<2;++m) for (int r=0;r<4;++r){ mrun[m][r] = -INFINITY; lrun[m][r] = 0.f; }

    // staging: lane covers k = it*16 + w*4 + g, d = lr*8 .. +7
    const int st_k0 = w*4 + g;     // + it*16
    const int st_d0 = lr*8;

    float4 stg[8];
    #pragma unroll
    for (int it = 0; it < 4; ++it) {
        const float* src = Kp + (size_t)(it*16 + st_k0)*DD + st_d0;
        stg[2*it]   = ((const float4*)src)[0];
        stg[2*it+1] = ((const float4*)src)[1];
    }

    for (int k0 = 0; k0 < SQ; k0 += KVB) {
        __syncthreads();   // all waves done with previous tile's kt/vt
        #pragma unroll
        for (int it = 0; it < 4; ++it) {
            const int kk = it*16 + st_k0;
            bf16x8 v = cvt8(stg[2*it], stg[2*it+1]);
            *(bf16x8*)&kt[kk][st_d0] = v;
            // V^T scatter with contiguity-preserving column swizzle
            #pragma unroll
            for (int d8 = 0; d8 < 8; ++d8) {
                const int d = st_d0 + d8;
                vt[d][kk ^ (8*((d>>3)&7))] = v[d8];
            }
        }
        __syncthreads();   // tile staged

        // prefetch next tile's global loads
        if (k0 + KVB < SQ) {
            #pragma unroll
            for (int it = 0; it < 4; ++it) {
                const float* src = Kp + (size_t)(k0 + KVB + it*16 + st_k0)*DD + st_d0;
                stg[2*it]   = ((const float4*)src)[0];
                stg[2*it+1] = ((const float4*)src)[1];
            }
        }

        // ---- QK^T : S[32q][64k] per wave ----
        f32x4 s[2][4];
        #pragma unroll
        for (int m=0;m<2;++m) for (int kc=0;kc<4;++kc) s[m][kc] = (f32x4)(0.0f);
        #pragma unroll
        for (int c = 0; c < 4; ++c) {
            #pragma unroll
            for (int kc = 0; kc < 4; ++kc) {
                // B-frag: col = lr (k-index kc*16+lr), kappa = d = 32c + g*8 + j
                bf16x8 bk = *(const bf16x8*)&kt[kc*16 + lr][32*c + g*8];
                s[0][kc] = MFMA(aq[0][c], bk, s[0][kc]);
                s[1][kc] = MFMA(aq[1][c], bk, s[1][kc]);
            }
        }

        // ---- online softmax (log2 domain), P -> LDS row-major ----
        #pragma unroll
        for (int m = 0; m < 2; ++m) {
            float corr[4];
            #pragma unroll
            for (int r = 0; r < 4; ++r) {
                float rm = fmaxf(fmaxf(s[m][0][r], s[m][1][r]),
                                 fmaxf(s[m][2][r], s[m][3][r]));
                rm = fmaxf(rm, __shfl_xor(rm, 1));
                rm = fmaxf(rm, __shfl_xor(rm, 2));
                rm = fmaxf(rm, __shfl_xor(rm, 4));
                rm = fmaxf(rm, __shfl_xor(rm, 8));
                float mnew = fmaxf(mrun[m][r], rm * CEXP);
                corr[r] = exp2f(mrun[m][r] - mnew);   // 0 on first tile
                mrun[m][r] = mnew;
            }
            float psum[4] = {0.f, 0.f, 0.f, 0.f};
            #pragma unroll
            for (int kc = 0; kc < 4; ++kc) {
                #pragma unroll
                for (int r = 0; r < 4; ++r) {
                    float p = exp2f(s[m][kc][r]*CEXP - mrun[m][r]);
                    psum[r] += p;
                    pt[w][16*m + g*4 + r][16*kc + lr] = (__bf16)p;  // P[q][k]
                }
            }
            #pragma unroll
            for (int r = 0; r < 4; ++r) lrun[m][r] = lrun[m][r]*corr[r] + psum[r];
            #pragma unroll
            for (int n = 0; n < 8; ++n) {
                f32x4 t = o[m][n];
                t[0]*=corr[0]; t[1]*=corr[1]; t[2]*=corr[2]; t[3]*=corr[3];
                o[m][n] = t;
            }
        }

        // ---- PV : O[32q][128d] += P * V ----
        // A-frag: P[16m + lr][kb*32 + g*8 + j]  (row-major, contiguous)
        bf16x8 ap[2][2];
        #pragma unroll
        for (int m = 0; m < 2; ++m)
            #pragma unroll
            for (int kb = 0; kb < 2; ++kb)
                ap[m][kb] = *(const bf16x8*)&pt[w][16*m + lr][kb*32 + g*8];

        #pragma unroll
        for (int n = 0; n < 8; ++n) {
            const int d = 16*n + lr;
            const int sw = 8*((d>>3)&7);
            #pragma unroll
            for (int kb = 0; kb < 2; ++kb) {
                // B-frag: col = d, kappa = k = kb*32 + g*8 + j (contiguous in vt)
                bf16x8 bv = *(const bf16x8*)&vt[d][(kb*32 + g*8) ^ sw];
                o[0][n] = MFMA(ap[0][kb], bv, o[0][n]);
                o[1][n] = MFMA(ap[1][kb], bv, o[1][n]);
            }
        }
    }

    // ---- epilogue: normalize and store ----
    #pragma unroll
    for (int m = 0; m < 2; ++m) {
        float inv[4];
        #pragma unroll
        for (int r = 0; r < 4; ++r) {
            float ls = lrun[m][r];
            ls += __shfl_xor(ls, 1);
            ls += __shfl_xor(ls, 2);
            ls += __shfl_xor(ls, 4);
            ls += __shfl_xor(ls, 8);
            inv[r] = 1.f / ls;
        }
        #pragma unroll
        for (int n = 0; n < 8; ++n) {
            #pragma unroll
            for (int r = 0; r < 4; ++r) {
                size_t row = (size_t)(q0w + 16*m + g*4 + r);
                Op[row*DD + 16*n + lr] = o[m][n][r] * inv[r];
            }
        }
    }
}

extern "C" void kernel_launch(void* const* d_in, const int* in_sizes, int n_in,
                              void* d_out, int out_size, void* d_ws, size_t ws_size,
                              hipStream_t stream) {
    const float* x1 = (const float*)d_in[0];
    const float* x2 = (const float*)d_in[1];
    float* out = (float*)d_out;
    dim3 grid(SQ / QB, 32);   // 16 q-blocks x (B*H = 32)
    dim3 block(256);
    attn_fwd<<<grid, block, 0, stream>>>(x1, x2, out);
}